// Round 5
// baseline (401.534 us; speedup 1.0000x reference)
//
#include <hip/hip_runtime.h>

// ---------------------------------------------------------------------------
// Stage sizes (floats)
//   x:       [32, 3, 128, 128]
//   y  (ws): [32, 32, 64, 64]   = 4,194,304   (conv+relu+pool out)
//   g  (ws): [32, 4096, 64]     = 8,388,608   (GCN out = "flat")
//   part(ws):[1024, 4096]       = 4,194,304   (fc1 split-K partials)
//   f1 (ws): [32, 128]          = 4,096
//   out:     [32, 101]
// ---------------------------------------------------------------------------

#define K_FC 262144

// ========================= Kernel 1: conv+relu+pool =========================
__global__ __launch_bounds__(256) void k_conv_pool(
    const float* __restrict__ x, const float* __restrict__ cw,
    const float* __restrict__ cb, float* __restrict__ y)
{
    __shared__ float wl[864];            // 32*3*3*3 weights
    __shared__ float tin[3 * 34 * 36];   // 34x34 input patch per channel, row pad->36

    int blk = blockIdx.x;
    int b = blk >> 4;
    int tile = blk & 15;
    int ph0 = (tile >> 2) << 4;
    int pw0 = (tile & 3) << 4;
    int t = threadIdx.x;

    for (int i = t; i < 864; i += 256) wl[i] = cw[i];

    int r0 = ph0 * 2 - 1;
    int c0 = pw0 * 2 - 1;
    for (int i = t; i < 3 * 34 * 34; i += 256) {
        int ci = i / 1156;
        int rem = i - ci * 1156;
        int yy = rem / 34;
        int xx = rem - yy * 34;
        int gr = r0 + yy, gc = c0 + xx;
        float v = 0.f;
        if (gr >= 0 && gr < 128 && gc >= 0 && gc < 128)
            v = x[((b * 3 + ci) * 128 + gr) * 128 + gc];
        tin[ci * 1224 + yy * 36 + xx] = v;
    }
    __syncthreads();

    int ph = t >> 4, pw = t & 15;
    float p[3][4][4];
#pragma unroll
    for (int ci = 0; ci < 3; ++ci)
#pragma unroll
        for (int dy = 0; dy < 4; ++dy) {
            const float2* row = (const float2*)&tin[ci * 1224 + (2 * ph + dy) * 36 + 2 * pw];
            float2 v0 = row[0], v1 = row[1];
            p[ci][dy][0] = v0.x; p[ci][dy][1] = v0.y;
            p[ci][dy][2] = v1.x; p[ci][dy][3] = v1.y;
        }

    int obase = (b * 32 * 64 + (ph0 + ph)) * 64 + pw0 + pw;
    for (int co = 0; co < 32; ++co) {
        float s00 = 0.f, s01 = 0.f, s10 = 0.f, s11 = 0.f;
#pragma unroll
        for (int ci = 0; ci < 3; ++ci)
#pragma unroll
            for (int ky = 0; ky < 3; ++ky)
#pragma unroll
                for (int kx = 0; kx < 3; ++kx) {
                    float wv = wl[co * 27 + ci * 9 + ky * 3 + kx];
                    s00 = fmaf(p[ci][ky][kx],         wv, s00);
                    s01 = fmaf(p[ci][ky][kx + 1],     wv, s01);
                    s10 = fmaf(p[ci][ky + 1][kx],     wv, s10);
                    s11 = fmaf(p[ci][ky + 1][kx + 1], wv, s11);
                }
        float m = fmaxf(fmaxf(s00, s01), fmaxf(s10, s11)) + cb[co];
        y[obase + co * 4096] = fmaxf(m, 0.f);
    }
}

// ============================ Kernel 2: GCN =================================
__device__ __forceinline__ float dinvf(int h, int w) {
    int d = 1 + (w > 0) + (w < 63) + (h > 0) + (h < 63);
    return rsqrtf((float)d);
}

__device__ __forceinline__ void acc4(const float* __restrict__ yb, int hq, int wq,
                                     int fh, float c,
                                     float4& a0, float4& a1, float4& a2, float4& a3)
{
    const float4* s = (const float4*)(yb + (((hq << 6) + wq) << 5) + fh);
    float4 v0 = s[0], v1 = s[1], v2 = s[2], v3 = s[3];
    a0.x = fmaf(c, v0.x, a0.x); a0.y = fmaf(c, v0.y, a0.y);
    a0.z = fmaf(c, v0.z, a0.z); a0.w = fmaf(c, v0.w, a0.w);
    a1.x = fmaf(c, v1.x, a1.x); a1.y = fmaf(c, v1.y, a1.y);
    a1.z = fmaf(c, v1.z, a1.z); a1.w = fmaf(c, v1.w, a1.w);
    a2.x = fmaf(c, v2.x, a2.x); a2.y = fmaf(c, v2.y, a2.y);
    a2.z = fmaf(c, v2.z, a2.z); a2.w = fmaf(c, v2.w, a2.w);
    a3.x = fmaf(c, v3.x, a3.x); a3.y = fmaf(c, v3.y, a3.y);
    a3.z = fmaf(c, v3.z, a3.z); a3.w = fmaf(c, v3.w, a3.w);
}

__global__ __launch_bounds__(256) void k_gcn(
    const float* __restrict__ y, const float* __restrict__ gw,
    const float* __restrict__ gb, float* __restrict__ g)
{
    __shared__ float zl[128 * 36];

    int blk = blockIdx.x;
    int b = blk >> 5;
    int r = blk & 31;
    int t = threadIdx.x;
    const float* yb = y + b * 131072;

    int lane = t & 63;
    int wave = t >> 6;
    float wreg[32];
#pragma unroll
    for (int f = 0; f < 32; ++f) wreg[f] = gw[f * 64 + lane];
    float bias = gb[lane];

    {
        int l = t >> 1;
        int fh = (t & 1) << 4;
        int h = 2 * r + (l >> 6);
        int w = l & 63;
        float dp = dinvf(h, w);
        float4 a0 = {0,0,0,0}, a1 = {0,0,0,0}, a2 = {0,0,0,0}, a3 = {0,0,0,0};
        acc4(yb, h, w, fh, dp * dp, a0, a1, a2, a3);
        if (w > 0)  acc4(yb, h, w - 1, fh, dp * dinvf(h, w - 1), a0, a1, a2, a3);
        if (w < 63) acc4(yb, h, w + 1, fh, dp * dinvf(h, w + 1), a0, a1, a2, a3);
        if (h > 0)  acc4(yb, h - 1, w, fh, dp * dinvf(h - 1, w), a0, a1, a2, a3);
        if (h < 63) acc4(yb, h + 1, w, fh, dp * dinvf(h + 1, w), a0, a1, a2, a3);
        float4* zrow = (float4*)&zl[l * 36 + fh];
        zrow[0] = a0; zrow[1] = a1; zrow[2] = a2; zrow[3] = a3;
    }
    __syncthreads();

    int l0 = wave << 5;
    int pbase = r * 128;
    float* gout = g + (size_t)b * 262144;
    for (int n = 0; n < 32; ++n) {
        int l = l0 + n;
        const float4* zz = (const float4*)&zl[l * 36];
        float acc = bias;
#pragma unroll
        for (int f4 = 0; f4 < 8; ++f4) {
            float4 zv = zz[f4];
            acc = fmaf(zv.x, wreg[f4 * 4 + 0], acc);
            acc = fmaf(zv.y, wreg[f4 * 4 + 1], acc);
            acc = fmaf(zv.z, wreg[f4 * 4 + 2], acc);
            acc = fmaf(zv.w, wreg[f4 * 4 + 3], acc);
        }
        gout[(pbase + l) * 64 + lane] = fmaxf(acc, 0.f);
    }
}

// ============================ Kernel 3: fc1 =================================
// partial[blk][32][128] = flat[32, k-slab] @ w1[k-slab, 128]^T
// grid 1024 (k-slab 256, 8 steps of 32), block 256, thread tile 4b x 8j,
// k-split x2 in-block (sub = t>>7).
//
// R4 restructure (profile: 82us, VALU 28%, HBM 26%, LDS-pipe ~37%, 4.2M bank
// conflicts -> latency/serialization-bound):
//   * W streams GLOBAL->REG via 8 row pointers (each (j,k) hits exactly one
//     thread; the 4 bg-threads reading the same addr are wave-merged). Kills
//     the whole Wl staging: its ds_writes, 8/12 of LDS reads, its conflicts.
//   * A tile (high reuse x128) stays in LDS, double-buffered (9.2 KB) ->
//     ONE barrier per step; the vmcnt drain at the barrier only hits loads
//     consumed in-step anyway.
//   * Summation order identical to previous version -> bitwise-same output.
__global__ __launch_bounds__(256, 4) void k_fc1(
    const float* __restrict__ flat, const float* __restrict__ w,
    float* __restrict__ partial)
{
    __shared__ float Al[2][32 * 36];   // A tile dbuf [b][k], pitch 36
    __shared__ float Rl[32 * 128];     // inter-half reduce buffer

    int t = threadIdx.x;
    int blk = blockIdx.x;
    int k0 = blk << 8;

    int sub = t >> 7;                // k-half within step
    int tt = t & 127;
    int bg = tt >> 4;                // 0..7
    int b0 = bg << 2;
    int jg = tt & 15;                // j = jg + 16*jj

    // W row pointers: rows jg+16*jj at column k0 + sub*16
    const float* wp[8];
#pragma unroll
    for (int jj = 0; jj < 8; ++jj)
        wp[jj] = w + (size_t)(jg + (jj << 4)) * K_FC + k0 + (sub << 4);

    // A staging address: thread stages row jb, 16B at column kq4
    int jb  = t >> 3;                // 0..31
    int kq4 = (t & 7) << 2;          // 0,4,...,28
    const float* asrc = flat + (size_t)jb * K_FC + k0 + kq4;
    int adst = jb * 36 + kq4;

    float acc[4][8];
#pragma unroll
    for (int i = 0; i < 4; ++i)
#pragma unroll
        for (int jj = 0; jj < 8; ++jj) acc[i][jj] = 0.f;

    // prologue: stage step-0 A tile
    {
        float4 v = *(const float4*)(asrc);
        *(float4*)&Al[0][adst] = v;
    }
    __syncthreads();

    for (int s = 0; s < 8; ++s) {
        int cur = s & 1;
        // issue next step's A load early; latency hides under compute
        float4 pa;
        if (s < 7) pa = *(const float4*)(asrc + ((s + 1) << 5));

        const float* al = &Al[cur][0];
        int soff = s << 5;
#pragma unroll
        for (int c = 0; c < 4; ++c) {
            int kk = (sub << 4) + (c << 2);
            float4 av[4];
#pragma unroll
            for (int i = 0; i < 4; ++i)
                av[i] = *(const float4*)&al[(b0 + i) * 36 + kk];
#pragma unroll
            for (int jj = 0; jj < 8; ++jj) {
                float4 wv = *(const float4*)(wp[jj] + soff + (c << 2));
#pragma unroll
                for (int i = 0; i < 4; ++i) {
                    acc[i][jj] = fmaf(av[i].x, wv.x, acc[i][jj]);
                    acc[i][jj] = fmaf(av[i].y, wv.y, acc[i][jj]);
                    acc[i][jj] = fmaf(av[i].z, wv.z, acc[i][jj]);
                    acc[i][jj] = fmaf(av[i].w, wv.w, acc[i][jj]);
                }
            }
        }
        // write next tile into the other buffer; readers start after barrier
        if (s < 7) *(float4*)&Al[cur ^ 1][adst] = pa;
        __syncthreads();
    }

    // inter-half reduce through LDS, then plain partial store
    if (sub == 1) {
#pragma unroll
        for (int i = 0; i < 4; ++i)
#pragma unroll
            for (int jj = 0; jj < 8; ++jj)
                Rl[((i << 3) + jj) * 128 + tt] = acc[i][jj];
    }
    __syncthreads();
    if (sub == 0) {
        float* pout = partial + ((size_t)blk << 12);
#pragma unroll
        for (int i = 0; i < 4; ++i)
#pragma unroll
            for (int jj = 0; jj < 8; ++jj)
                pout[(b0 + i) * 128 + jg + (jj << 4)] =
                    acc[i][jj] + Rl[((i << 3) + jj) * 128 + tt];
    }
}

// ==================== Kernel 3b: split-K partial reduce =====================
// f1[e] = sum_ns partial[ns][e];  grid 256, 4 float4-elements per block
__global__ __launch_bounds__(256) void k_red(
    const float* __restrict__ partial, float* __restrict__ f1)
{
    __shared__ float4 Sl[256];
    int t = threadIdx.x;
    int e4 = (blockIdx.x << 2) + (t & 3);
    int ng = t >> 2;
    const float4* p = (const float4*)partial;
    float4 a = {0.f, 0.f, 0.f, 0.f};
#pragma unroll
    for (int i = 0; i < 16; ++i) {
        int ns = ng + (i << 6);
        float4 v = p[(size_t)ns * 1024 + e4];
        a.x += v.x; a.y += v.y; a.z += v.z; a.w += v.w;
    }
    Sl[t] = a;
    __syncthreads();
    for (int off = 128; off >= 4; off >>= 1) {
        if (t < off) {
            float4 u = Sl[t], v = Sl[t + off];
            u.x += v.x; u.y += v.y; u.z += v.z; u.w += v.w;
            Sl[t] = u;
        }
        __syncthreads();
    }
    if (t < 4) ((float4*)f1)[(blockIdx.x << 2) + t] = Sl[t];
}

// ============================ Kernel 4: fc2 =================================
__global__ __launch_bounds__(256) void k_fc2(
    const float* __restrict__ f1, const float* __restrict__ b1,
    const float* __restrict__ w2, const float* __restrict__ b2,
    float* __restrict__ out)
{
    int idx = blockIdx.x * 256 + threadIdx.x;
    if (idx >= 32 * 101) return;
    int b = idx / 101;
    int c = idx - b * 101;
    const float4* fp = (const float4*)(f1 + b * 128);
    const float4* bp = (const float4*)b1;
    const float4* wp = (const float4*)(w2 + c * 128);
    float acc = b2[c];
#pragma unroll
    for (int q = 0; q < 32; ++q) {
        float4 f = fp[q], bb = bp[q], ww = wp[q];
        acc = fmaf(fmaxf(f.x + bb.x, 0.f), ww.x, acc);
        acc = fmaf(fmaxf(f.y + bb.y, 0.f), ww.y, acc);
        acc = fmaf(fmaxf(f.z + bb.z, 0.f), ww.z, acc);
        acc = fmaf(fmaxf(f.w + bb.w, 0.f), ww.w, acc);
    }
    out[idx] = acc;
}

// ================================ launch ====================================
extern "C" void kernel_launch(void* const* d_in, const int* in_sizes, int n_in,
                              void* d_out, int out_size, void* d_ws, size_t ws_size,
                              hipStream_t stream)
{
    const float* x  = (const float*)d_in[0];
    const float* cw = (const float*)d_in[1];
    const float* cb = (const float*)d_in[2];
    const float* gw = (const float*)d_in[3];
    const float* gb = (const float*)d_in[4];
    const float* w1 = (const float*)d_in[5];
    const float* b1 = (const float*)d_in[6];
    const float* w2 = (const float*)d_in[7];
    const float* b2 = (const float*)d_in[8];
    float* out = (float*)d_out;

    float* y       = (float*)d_ws;           // 4,194,304
    float* g       = y + 4194304;            // 8,388,608
    float* partial = g + 8388608;            // 4,194,304
    float* f1      = partial + 4194304;      // 4,096

    k_conv_pool<<<512, 256, 0, stream>>>(x, cw, cb, y);
    k_gcn<<<1024, 256, 0, stream>>>(y, gw, gb, g);
    k_fc1<<<1024, 256, 0, stream>>>(g, w1, partial);
    k_red<<<256, 256, 0, stream>>>(partial, f1);
    k_fc2<<<13, 256, 0, stream>>>(f1, b1, w2, b2, out);
}

// Round 6
// 284.441 us; speedup vs baseline: 1.4117x; 1.4117x over previous
//
#include <hip/hip_runtime.h>

// ---------------------------------------------------------------------------
// Stage sizes (floats)
//   x:       [32, 3, 128, 128]
//   y  (ws): [32, 32, 64, 64]   = 4,194,304   (conv+relu+pool out)
//   g  (ws): [32, 4096, 64]     = 8,388,608   (GCN out = "flat")
//   part(ws):[1024, 4096]       = 4,194,304   (fc1 split-K partials)
//   f1 (ws): [32, 128]          = 4,096
//   out:     [32, 101]
// ---------------------------------------------------------------------------

#define K_FC 262144

// direct global->LDS DMA, 16B per lane; LDS dest = uniform base + lane*16
#define GLOAD_LDS16(gp, lp)                                                  \
    __builtin_amdgcn_global_load_lds(                                        \
        (const __attribute__((address_space(1))) void*)(gp),                 \
        (__attribute__((address_space(3))) void*)(lp), 16, 0, 0)

// ========================= Kernel 1: conv+relu+pool =========================
__global__ __launch_bounds__(256) void k_conv_pool(
    const float* __restrict__ x, const float* __restrict__ cw,
    const float* __restrict__ cb, float* __restrict__ y)
{
    __shared__ float wl[864];            // 32*3*3*3 weights
    __shared__ float tin[3 * 34 * 36];   // 34x34 input patch per channel, row pad->36

    int blk = blockIdx.x;
    int b = blk >> 4;
    int tile = blk & 15;
    int ph0 = (tile >> 2) << 4;
    int pw0 = (tile & 3) << 4;
    int t = threadIdx.x;

    for (int i = t; i < 864; i += 256) wl[i] = cw[i];

    int r0 = ph0 * 2 - 1;
    int c0 = pw0 * 2 - 1;
    for (int i = t; i < 3 * 34 * 34; i += 256) {
        int ci = i / 1156;
        int rem = i - ci * 1156;
        int yy = rem / 34;
        int xx = rem - yy * 34;
        int gr = r0 + yy, gc = c0 + xx;
        float v = 0.f;
        if (gr >= 0 && gr < 128 && gc >= 0 && gc < 128)
            v = x[((b * 3 + ci) * 128 + gr) * 128 + gc];
        tin[ci * 1224 + yy * 36 + xx] = v;
    }
    __syncthreads();

    int ph = t >> 4, pw = t & 15;
    float p[3][4][4];
#pragma unroll
    for (int ci = 0; ci < 3; ++ci)
#pragma unroll
        for (int dy = 0; dy < 4; ++dy) {
            const float2* row = (const float2*)&tin[ci * 1224 + (2 * ph + dy) * 36 + 2 * pw];
            float2 v0 = row[0], v1 = row[1];
            p[ci][dy][0] = v0.x; p[ci][dy][1] = v0.y;
            p[ci][dy][2] = v1.x; p[ci][dy][3] = v1.y;
        }

    int obase = (b * 32 * 64 + (ph0 + ph)) * 64 + pw0 + pw;
    for (int co = 0; co < 32; ++co) {
        float s00 = 0.f, s01 = 0.f, s10 = 0.f, s11 = 0.f;
#pragma unroll
        for (int ci = 0; ci < 3; ++ci)
#pragma unroll
            for (int ky = 0; ky < 3; ++ky)
#pragma unroll
                for (int kx = 0; kx < 3; ++kx) {
                    float wv = wl[co * 27 + ci * 9 + ky * 3 + kx];
                    s00 = fmaf(p[ci][ky][kx],         wv, s00);
                    s01 = fmaf(p[ci][ky][kx + 1],     wv, s01);
                    s10 = fmaf(p[ci][ky + 1][kx],     wv, s10);
                    s11 = fmaf(p[ci][ky + 1][kx + 1], wv, s11);
                }
        float m = fmaxf(fmaxf(s00, s01), fmaxf(s10, s11)) + cb[co];
        y[obase + co * 4096] = fmaxf(m, 0.f);
    }
}

// ============================ Kernel 2: GCN =================================
__device__ __forceinline__ float dinvf(int h, int w) {
    int d = 1 + (w > 0) + (w < 63) + (h > 0) + (h < 63);
    return rsqrtf((float)d);
}

__device__ __forceinline__ void acc4(const float* __restrict__ yb, int hq, int wq,
                                     int fh, float c,
                                     float4& a0, float4& a1, float4& a2, float4& a3)
{
    const float4* s = (const float4*)(yb + (((hq << 6) + wq) << 5) + fh);
    float4 v0 = s[0], v1 = s[1], v2 = s[2], v3 = s[3];
    a0.x = fmaf(c, v0.x, a0.x); a0.y = fmaf(c, v0.y, a0.y);
    a0.z = fmaf(c, v0.z, a0.z); a0.w = fmaf(c, v0.w, a0.w);
    a1.x = fmaf(c, v1.x, a1.x); a1.y = fmaf(c, v1.y, a1.y);
    a1.z = fmaf(c, v1.z, a1.z); a1.w = fmaf(c, v1.w, a1.w);
    a2.x = fmaf(c, v2.x, a2.x); a2.y = fmaf(c, v2.y, a2.y);
    a2.z = fmaf(c, v2.z, a2.z); a2.w = fmaf(c, v2.w, a2.w);
    a3.x = fmaf(c, v3.x, a3.x); a3.y = fmaf(c, v3.y, a3.y);
    a3.z = fmaf(c, v3.z, a3.z); a3.w = fmaf(c, v3.w, a3.w);
}

__global__ __launch_bounds__(256) void k_gcn(
    const float* __restrict__ y, const float* __restrict__ gw,
    const float* __restrict__ gb, float* __restrict__ g)
{
    __shared__ float zl[128 * 36];

    int blk = blockIdx.x;
    int b = blk >> 5;
    int r = blk & 31;
    int t = threadIdx.x;
    const float* yb = y + b * 131072;

    int lane = t & 63;
    int wave = t >> 6;
    float wreg[32];
#pragma unroll
    for (int f = 0; f < 32; ++f) wreg[f] = gw[f * 64 + lane];
    float bias = gb[lane];

    {
        int l = t >> 1;
        int fh = (t & 1) << 4;
        int h = 2 * r + (l >> 6);
        int w = l & 63;
        float dp = dinvf(h, w);
        float4 a0 = {0,0,0,0}, a1 = {0,0,0,0}, a2 = {0,0,0,0}, a3 = {0,0,0,0};
        acc4(yb, h, w, fh, dp * dp, a0, a1, a2, a3);
        if (w > 0)  acc4(yb, h, w - 1, fh, dp * dinvf(h, w - 1), a0, a1, a2, a3);
        if (w < 63) acc4(yb, h, w + 1, fh, dp * dinvf(h, w + 1), a0, a1, a2, a3);
        if (h > 0)  acc4(yb, h - 1, w, fh, dp * dinvf(h - 1, w), a0, a1, a2, a3);
        if (h < 63) acc4(yb, h + 1, w, fh, dp * dinvf(h + 1, w), a0, a1, a2, a3);
        float4* zrow = (float4*)&zl[l * 36 + fh];
        zrow[0] = a0; zrow[1] = a1; zrow[2] = a2; zrow[3] = a3;
    }
    __syncthreads();

    int l0 = wave << 5;
    int pbase = r * 128;
    float* gout = g + (size_t)b * 262144;
    for (int n = 0; n < 32; ++n) {
        int l = l0 + n;
        const float4* zz = (const float4*)&zl[l * 36];
        float acc = bias;
#pragma unroll
        for (int f4 = 0; f4 < 8; ++f4) {
            float4 zv = zz[f4];
            acc = fmaf(zv.x, wreg[f4 * 4 + 0], acc);
            acc = fmaf(zv.y, wreg[f4 * 4 + 1], acc);
            acc = fmaf(zv.z, wreg[f4 * 4 + 2], acc);
            acc = fmaf(zv.w, wreg[f4 * 4 + 3], acc);
        }
        gout[(pbase + l) * 64 + lane] = fmaxf(acc, 0.f);
    }
}

// ============================ Kernel 3: fc1 =================================
// partial[blk][32][128] = flat[32, k-slab] @ w1[k-slab, 128]^T
// grid 1024 (k-slab 256, 8 steps of 32), block 256, thread tile 4b x 8j,
// k-split x2 in-block (sub = t>>7). Same accumulation order as the measured
// 82us version -> bitwise-identical output.
//
// R6 (post-mortem R5: W->reg streaming destroyed coalescing, 12% VALU, 2.4x
// slower; REVERTED. R4-measured costs: staging writes + 4.2M conflicts + 2
// barriers/step):
//   * W staged via global_load_lds DMA (16B/lane): no VGPR round-trip, no
//     ds_writes, linear conflict-free LDS writes, coalesced 128B global runs.
//   * T2 swizzle BOTH-sides (rule #21): linear DMA dest; source per-lane
//     address pre-permuted (phys_k = k ^ ((row&7)<<2)); read applies same
//     XOR -> read instr spans all 8 bank-quads (2-way = free).
//   * Wl+Al double-buffered -> ONE barrier/step; next-step DMA issued before
//     compute, drains at the end-of-step barrier (T14 depth-1).
//   * LDS 41KB -> 3 blocks/CU (12 waves/CU, same occupancy as measured 38%).
__global__ __launch_bounds__(256, 3) void k_fc1(
    const float* __restrict__ flat, const float* __restrict__ w,
    float* __restrict__ partial)
{
    __shared__ float Wl[2][4096];   // [dbuf][128 rows x 32 cols], XOR-swizzled
    __shared__ float Al[2][1152];   // [dbuf][32 rows x pitch 36]

    int t = threadIdx.x;
    int blk = blockIdx.x;
    int k0 = blk << 8;

    int sub = t >> 7;                // k-half within step
    int tt = t & 127;
    int bg = tt >> 4;                // 0..7
    int b0 = bg << 2;
    int jg = tt & 15;                // j = jg + 16*jj

    // --- W DMA staging: wave stages rows wave*32 .. +31, 4 calls of 8 rows ---
    int wave = t >> 6, lane = t & 63;
    // phys slot (row, (lane&7)) holds logical k-group (lane&7)^(row&7); row&7 == (lane>>3)&7
    int kxor = ((lane & 7) ^ ((lane >> 3) & 7)) << 2;
    const float* wsrc[4];
#pragma unroll
    for (int cc = 0; cc < 4; ++cc) {
        int row = (wave << 5) + (cc << 3) + (lane >> 3);
        wsrc[cc] = w + (size_t)row * K_FC + k0 + kxor;
    }
    int ldst = wave << 10;           // word offset of this wave's 32-row region

    // --- A staging (reg->LDS, 1 float4/thread, pitch 36: measured conflict-free) ---
    int jb  = t >> 3;                // 0..31
    int kq4 = (t & 7) << 2;
    const float* asrc = flat + (size_t)jb * K_FC + k0 + kq4;
    int adst = jb * 36 + kq4;

    int rx = (jg & 7) << 2;          // read-side swizzle term

    float acc[4][8];
#pragma unroll
    for (int i = 0; i < 4; ++i)
#pragma unroll
        for (int jj = 0; jj < 8; ++jj) acc[i][jj] = 0.f;

    // prologue: stage step-0 tiles
#pragma unroll
    for (int cc = 0; cc < 4; ++cc)
        GLOAD_LDS16(wsrc[cc], &Wl[0][ldst + (cc << 8)]);
    *(float4*)&Al[0][adst] = *(const float4*)asrc;
    __syncthreads();

    for (int s = 0; s < 8; ++s) {
        int cur = s & 1;
        float4 pa;
        if (s < 7) {
            int so = (s + 1) << 5;
#pragma unroll
            for (int cc = 0; cc < 4; ++cc)
                GLOAD_LDS16(wsrc[cc] + so, &Wl[cur ^ 1][ldst + (cc << 8)]);
            pa = *(const float4*)(asrc + so);
        }

        const float* al = Al[cur];
        const float* wlp = Wl[cur];
#pragma unroll
        for (int c = 0; c < 4; ++c) {
            int kk = (sub << 4) + (c << 2);
            int wkk = kk ^ rx;
            float4 av[4];
#pragma unroll
            for (int i = 0; i < 4; ++i)
                av[i] = *(const float4*)&al[(b0 + i) * 36 + kk];
#pragma unroll
            for (int jj = 0; jj < 8; ++jj) {
                float4 wv = *(const float4*)&wlp[((jg + (jj << 4)) << 5) + wkk];
#pragma unroll
                for (int i = 0; i < 4; ++i) {
                    acc[i][jj] = fmaf(av[i].x, wv.x, acc[i][jj]);
                    acc[i][jj] = fmaf(av[i].y, wv.y, acc[i][jj]);
                    acc[i][jj] = fmaf(av[i].z, wv.z, acc[i][jj]);
                    acc[i][jj] = fmaf(av[i].w, wv.w, acc[i][jj]);
                }
            }
        }
        if (s < 7) *(float4*)&Al[cur ^ 1][adst] = pa;
        __syncthreads();
    }

    // inter-half reduce through LDS (reuse Wl[0]: step 7 computed from Wl[1],
    // and no prefetch wrote Wl[0] on the last step), then plain partial store
    float* Rl = &Wl[0][0];
    if (sub == 1) {
#pragma unroll
        for (int i = 0; i < 4; ++i)
#pragma unroll
            for (int jj = 0; jj < 8; ++jj)
                Rl[((i << 3) + jj) * 128 + tt] = acc[i][jj];
    }
    __syncthreads();
    if (sub == 0) {
        float* pout = partial + ((size_t)blk << 12);
#pragma unroll
        for (int i = 0; i < 4; ++i)
#pragma unroll
            for (int jj = 0; jj < 8; ++jj)
                pout[(b0 + i) * 128 + jg + (jj << 4)] =
                    acc[i][jj] + Rl[((i << 3) + jj) * 128 + tt];
    }
}

// ==================== Kernel 3b: split-K partial reduce =====================
// f1[e] = sum_ns partial[ns][e];  grid 256, 4 float4-elements per block
__global__ __launch_bounds__(256) void k_red(
    const float* __restrict__ partial, float* __restrict__ f1)
{
    __shared__ float4 Sl[256];
    int t = threadIdx.x;
    int e4 = (blockIdx.x << 2) + (t & 3);
    int ng = t >> 2;
    const float4* p = (const float4*)partial;
    float4 a = {0.f, 0.f, 0.f, 0.f};
#pragma unroll
    for (int i = 0; i < 16; ++i) {
        int ns = ng + (i << 6);
        float4 v = p[(size_t)ns * 1024 + e4];
        a.x += v.x; a.y += v.y; a.z += v.z; a.w += v.w;
    }
    Sl[t] = a;
    __syncthreads();
    for (int off = 128; off >= 4; off >>= 1) {
        if (t < off) {
            float4 u = Sl[t], v = Sl[t + off];
            u.x += v.x; u.y += v.y; u.z += v.z; u.w += v.w;
            Sl[t] = u;
        }
        __syncthreads();
    }
    if (t < 4) ((float4*)f1)[(blockIdx.x << 2) + t] = Sl[t];
}

// ============================ Kernel 4: fc2 =================================
__global__ __launch_bounds__(256) void k_fc2(
    const float* __restrict__ f1, const float* __restrict__ b1,
    const float* __restrict__ w2, const float* __restrict__ b2,
    float* __restrict__ out)
{
    int idx = blockIdx.x * 256 + threadIdx.x;
    if (idx >= 32 * 101) return;
    int b = idx / 101;
    int c = idx - b * 101;
    const float4* fp = (const float4*)(f1 + b * 128);
    const float4* bp = (const float4*)b1;
    const float4* wp = (const float4*)(w2 + c * 128);
    float acc = b2[c];
#pragma unroll
    for (int q = 0; q < 32; ++q) {
        float4 f = fp[q], bb = bp[q], ww = wp[q];
        acc = fmaf(fmaxf(f.x + bb.x, 0.f), ww.x, acc);
        acc = fmaf(fmaxf(f.y + bb.y, 0.f), ww.y, acc);
        acc = fmaf(fmaxf(f.z + bb.z, 0.f), ww.z, acc);
        acc = fmaf(fmaxf(f.w + bb.w, 0.f), ww.w, acc);
    }
    out[idx] = acc;
}

// ================================ launch ====================================
extern "C" void kernel_launch(void* const* d_in, const int* in_sizes, int n_in,
                              void* d_out, int out_size, void* d_ws, size_t ws_size,
                              hipStream_t stream)
{
    const float* x  = (const float*)d_in[0];
    const float* cw = (const float*)d_in[1];
    const float* cb = (const float*)d_in[2];
    const float* gw = (const float*)d_in[3];
    const float* gb = (const float*)d_in[4];
    const float* w1 = (const float*)d_in[5];
    const float* b1 = (const float*)d_in[6];
    const float* w2 = (const float*)d_in[7];
    const float* b2 = (const float*)d_in[8];
    float* out = (float*)d_out;

    float* y       = (float*)d_ws;           // 4,194,304
    float* g       = y + 4194304;            // 8,388,608
    float* partial = g + 8388608;            // 4,194,304
    float* f1      = partial + 4194304;      // 4,096

    k_conv_pool<<<512, 256, 0, stream>>>(x, cw, cb, y);
    k_gcn<<<1024, 256, 0, stream>>>(y, gw, gb, g);
    k_fc1<<<1024, 256, 0, stream>>>(g, w1, partial);
    k_red<<<256, 256, 0, stream>>>(partial, f1);
    k_fc2<<<13, 256, 0, stream>>>(f1, b1, w2, b2, out);
}

// Round 7
// 270.070 us; speedup vs baseline: 1.4868x; 1.0532x over previous
//
#include <hip/hip_runtime.h>

// ---------------------------------------------------------------------------
// Stage sizes (floats)
//   x:       [32, 3, 128, 128]
//   y  (ws): [32, 32, 64, 64]   = 4,194,304   (conv+relu+pool out)
//   g  (ws): [32, 4096, 64]     = 8,388,608   (GCN out = "flat")
//   part(ws):[512, 4096]        = 2,097,152   (fc1 split-K partials)
//   f1 (ws): [32, 128]          = 4,096
//   out:     [32, 101]
// ---------------------------------------------------------------------------

#define K_FC 262144

// direct global->LDS DMA, 16B per lane; LDS dest = uniform base + lane*16
#define GLOAD_LDS16(gp, lp)                                                  \
    __builtin_amdgcn_global_load_lds(                                        \
        (const __attribute__((address_space(1))) void*)(gp),                 \
        (__attribute__((address_space(3))) void*)(lp), 16, 0, 0)

// ========================= Kernel 1: conv+relu+pool =========================
__global__ __launch_bounds__(256) void k_conv_pool(
    const float* __restrict__ x, const float* __restrict__ cw,
    const float* __restrict__ cb, float* __restrict__ y)
{
    __shared__ float wl[864];            // 32*3*3*3 weights
    __shared__ float tin[3 * 34 * 36];   // 34x34 input patch per channel, row pad->36

    int blk = blockIdx.x;
    int b = blk >> 4;
    int tile = blk & 15;
    int ph0 = (tile >> 2) << 4;
    int pw0 = (tile & 3) << 4;
    int t = threadIdx.x;

    for (int i = t; i < 864; i += 256) wl[i] = cw[i];

    int r0 = ph0 * 2 - 1;
    int c0 = pw0 * 2 - 1;
    for (int i = t; i < 3 * 34 * 34; i += 256) {
        int ci = i / 1156;
        int rem = i - ci * 1156;
        int yy = rem / 34;
        int xx = rem - yy * 34;
        int gr = r0 + yy, gc = c0 + xx;
        float v = 0.f;
        if (gr >= 0 && gr < 128 && gc >= 0 && gc < 128)
            v = x[((b * 3 + ci) * 128 + gr) * 128 + gc];
        tin[ci * 1224 + yy * 36 + xx] = v;
    }
    __syncthreads();

    int ph = t >> 4, pw = t & 15;
    float p[3][4][4];
#pragma unroll
    for (int ci = 0; ci < 3; ++ci)
#pragma unroll
        for (int dy = 0; dy < 4; ++dy) {
            const float2* row = (const float2*)&tin[ci * 1224 + (2 * ph + dy) * 36 + 2 * pw];
            float2 v0 = row[0], v1 = row[1];
            p[ci][dy][0] = v0.x; p[ci][dy][1] = v0.y;
            p[ci][dy][2] = v1.x; p[ci][dy][3] = v1.y;
        }

    int obase = (b * 32 * 64 + (ph0 + ph)) * 64 + pw0 + pw;
    for (int co = 0; co < 32; ++co) {
        float s00 = 0.f, s01 = 0.f, s10 = 0.f, s11 = 0.f;
#pragma unroll
        for (int ci = 0; ci < 3; ++ci)
#pragma unroll
            for (int ky = 0; ky < 3; ++ky)
#pragma unroll
                for (int kx = 0; kx < 3; ++kx) {
                    float wv = wl[co * 27 + ci * 9 + ky * 3 + kx];
                    s00 = fmaf(p[ci][ky][kx],         wv, s00);
                    s01 = fmaf(p[ci][ky][kx + 1],     wv, s01);
                    s10 = fmaf(p[ci][ky + 1][kx],     wv, s10);
                    s11 = fmaf(p[ci][ky + 1][kx + 1], wv, s11);
                }
        float m = fmaxf(fmaxf(s00, s01), fmaxf(s10, s11)) + cb[co];
        y[obase + co * 4096] = fmaxf(m, 0.f);
    }
}

// ============================ Kernel 2: GCN =================================
__device__ __forceinline__ float dinvf(int h, int w) {
    int d = 1 + (w > 0) + (w < 63) + (h > 0) + (h < 63);
    return rsqrtf((float)d);
}

__device__ __forceinline__ void acc4(const float* __restrict__ yb, int hq, int wq,
                                     int fh, float c,
                                     float4& a0, float4& a1, float4& a2, float4& a3)
{
    const float4* s = (const float4*)(yb + (((hq << 6) + wq) << 5) + fh);
    float4 v0 = s[0], v1 = s[1], v2 = s[2], v3 = s[3];
    a0.x = fmaf(c, v0.x, a0.x); a0.y = fmaf(c, v0.y, a0.y);
    a0.z = fmaf(c, v0.z, a0.z); a0.w = fmaf(c, v0.w, a0.w);
    a1.x = fmaf(c, v1.x, a1.x); a1.y = fmaf(c, v1.y, a1.y);
    a1.z = fmaf(c, v1.z, a1.z); a1.w = fmaf(c, v1.w, a1.w);
    a2.x = fmaf(c, v2.x, a2.x); a2.y = fmaf(c, v2.y, a2.y);
    a2.z = fmaf(c, v2.z, a2.z); a2.w = fmaf(c, v2.w, a2.w);
    a3.x = fmaf(c, v3.x, a3.x); a3.y = fmaf(c, v3.y, a3.y);
    a3.z = fmaf(c, v3.z, a3.z); a3.w = fmaf(c, v3.w, a3.w);
}

__global__ __launch_bounds__(256) void k_gcn(
    const float* __restrict__ y, const float* __restrict__ gw,
    const float* __restrict__ gb, float* __restrict__ g)
{
    __shared__ float zl[128 * 36];

    int blk = blockIdx.x;
    int b = blk >> 5;
    int r = blk & 31;
    int t = threadIdx.x;
    const float* yb = y + b * 131072;

    int lane = t & 63;
    int wave = t >> 6;
    float wreg[32];
#pragma unroll
    for (int f = 0; f < 32; ++f) wreg[f] = gw[f * 64 + lane];
    float bias = gb[lane];

    {
        int l = t >> 1;
        int fh = (t & 1) << 4;
        int h = 2 * r + (l >> 6);
        int w = l & 63;
        float dp = dinvf(h, w);
        float4 a0 = {0,0,0,0}, a1 = {0,0,0,0}, a2 = {0,0,0,0}, a3 = {0,0,0,0};
        acc4(yb, h, w, fh, dp * dp, a0, a1, a2, a3);
        if (w > 0)  acc4(yb, h, w - 1, fh, dp * dinvf(h, w - 1), a0, a1, a2, a3);
        if (w < 63) acc4(yb, h, w + 1, fh, dp * dinvf(h, w + 1), a0, a1, a2, a3);
        if (h > 0)  acc4(yb, h - 1, w, fh, dp * dinvf(h - 1, w), a0, a1, a2, a3);
        if (h < 63) acc4(yb, h + 1, w, fh, dp * dinvf(h + 1, w), a0, a1, a2, a3);
        float4* zrow = (float4*)&zl[l * 36 + fh];
        zrow[0] = a0; zrow[1] = a1; zrow[2] = a2; zrow[3] = a3;
    }
    __syncthreads();

    int l0 = wave << 5;
    int pbase = r * 128;
    float* gout = g + (size_t)b * 262144;
    for (int n = 0; n < 32; ++n) {
        int l = l0 + n;
        const float4* zz = (const float4*)&zl[l * 36];
        float acc = bias;
#pragma unroll
        for (int f4 = 0; f4 < 8; ++f4) {
            float4 zv = zz[f4];
            acc = fmaf(zv.x, wreg[f4 * 4 + 0], acc);
            acc = fmaf(zv.y, wreg[f4 * 4 + 1], acc);
            acc = fmaf(zv.z, wreg[f4 * 4 + 2], acc);
            acc = fmaf(zv.w, wreg[f4 * 4 + 3], acc);
        }
        gout[(pbase + l) * 64 + lane] = fmaxf(acc, 0.f);
    }
}

// ============================ Kernel 3: fc1 =================================
// partial[blk][32][128] = flat[32, k-slab] @ w1[k-slab, 128]^T
// R7: grid 512 (k-slab 512, 16 steps of 32), block 256, thread tile 4b x 8j,
// k-split x2 in-block (sub = t>>7). Step structure/LDS/swizzle identical to
// the R6 version (DMA-staged W, dbuf, one barrier/step).
//
// R6 post-mortem: fc1 ~71us inferred; effective W read rate only ~1.9 TB/s.
// Theory: per (row, step) we fetch a scattered 128B granule, rows 1MB apart;
// with slab 256 a block touches only 1KB/row -> every granule opens a new
// DRAM row. Slab 512 makes each block's 16 successive steps walk 2KB
// CONTIGUOUS per row -> DRAM row-buffer hits across steps. 512 blocks = 2/CU
// (8 waves/CU); in-flight ~32KB/CU > BWxlat ~22KB -> still latency-covered.
__global__ __launch_bounds__(256, 3) void k_fc1(
    const float* __restrict__ flat, const float* __restrict__ w,
    float* __restrict__ partial)
{
    __shared__ float Wl[2][4096];   // [dbuf][128 rows x 32 cols], XOR-swizzled
    __shared__ float Al[2][1152];   // [dbuf][32 rows x pitch 36]

    int t = threadIdx.x;
    int blk = blockIdx.x;
    int k0 = blk << 9;               // slab 512 floats

    int sub = t >> 7;                // k-half within step
    int tt = t & 127;
    int bg = tt >> 4;                // 0..7
    int b0 = bg << 2;
    int jg = tt & 15;                // j = jg + 16*jj

    // --- W DMA staging: wave stages rows wave*32 .. +31, 4 calls of 8 rows ---
    int wave = t >> 6, lane = t & 63;
    // phys slot (row, (lane&7)) holds logical k-group (lane&7)^(row&7); row&7 == (lane>>3)&7
    int kxor = ((lane & 7) ^ ((lane >> 3) & 7)) << 2;
    const float* wsrc[4];
#pragma unroll
    for (int cc = 0; cc < 4; ++cc) {
        int row = (wave << 5) + (cc << 3) + (lane >> 3);
        wsrc[cc] = w + (size_t)row * K_FC + k0 + kxor;
    }
    int ldst = wave << 10;           // word offset of this wave's 32-row region

    // --- A staging (reg->LDS, 1 float4/thread, pitch 36) ---
    int jb  = t >> 3;                // 0..31
    int kq4 = (t & 7) << 2;
    const float* asrc = flat + (size_t)jb * K_FC + k0 + kq4;
    int adst = jb * 36 + kq4;

    int rx = (jg & 7) << 2;          // read-side swizzle term

    float acc[4][8];
#pragma unroll
    for (int i = 0; i < 4; ++i)
#pragma unroll
        for (int jj = 0; jj < 8; ++jj) acc[i][jj] = 0.f;

    // prologue: stage step-0 tiles
#pragma unroll
    for (int cc = 0; cc < 4; ++cc)
        GLOAD_LDS16(wsrc[cc], &Wl[0][ldst + (cc << 8)]);
    *(float4*)&Al[0][adst] = *(const float4*)asrc;
    __syncthreads();

    for (int s = 0; s < 16; ++s) {
        int cur = s & 1;
        float4 pa;
        if (s < 15) {
            int so = (s + 1) << 5;
#pragma unroll
            for (int cc = 0; cc < 4; ++cc)
                GLOAD_LDS16(wsrc[cc] + so, &Wl[cur ^ 1][ldst + (cc << 8)]);
            pa = *(const float4*)(asrc + so);
        }

        const float* al = Al[cur];
        const float* wlp = Wl[cur];
#pragma unroll
        for (int c = 0; c < 4; ++c) {
            int kk = (sub << 4) + (c << 2);
            int wkk = kk ^ rx;
            float4 av[4];
#pragma unroll
            for (int i = 0; i < 4; ++i)
                av[i] = *(const float4*)&al[(b0 + i) * 36 + kk];
#pragma unroll
            for (int jj = 0; jj < 8; ++jj) {
                float4 wv = *(const float4*)&wlp[((jg + (jj << 4)) << 5) + wkk];
#pragma unroll
                for (int i = 0; i < 4; ++i) {
                    acc[i][jj] = fmaf(av[i].x, wv.x, acc[i][jj]);
                    acc[i][jj] = fmaf(av[i].y, wv.y, acc[i][jj]);
                    acc[i][jj] = fmaf(av[i].z, wv.z, acc[i][jj]);
                    acc[i][jj] = fmaf(av[i].w, wv.w, acc[i][jj]);
                }
            }
        }
        if (s < 15) *(float4*)&Al[cur ^ 1][adst] = pa;
        __syncthreads();
    }

    // inter-half reduce through LDS (reuse Wl[0]: step 15 computed from Wl[1],
    // and no prefetch wrote Wl[0] on the last step), then plain partial store
    float* Rl = &Wl[0][0];
    if (sub == 1) {
#pragma unroll
        for (int i = 0; i < 4; ++i)
#pragma unroll
            for (int jj = 0; jj < 8; ++jj)
                Rl[((i << 3) + jj) * 128 + tt] = acc[i][jj];
    }
    __syncthreads();
    if (sub == 0) {
        float* pout = partial + ((size_t)blk << 12);
#pragma unroll
        for (int i = 0; i < 4; ++i)
#pragma unroll
            for (int jj = 0; jj < 8; ++jj)
                pout[(b0 + i) * 128 + jg + (jj << 4)] =
                    acc[i][jj] + Rl[((i << 3) + jj) * 128 + tt];
    }
}

// ==================== Kernel 3b: split-K partial reduce =====================
// f1[e] = sum_ns partial[ns][e];  512 slabs now; grid 256, 4 float4/block
__global__ __launch_bounds__(256) void k_red(
    const float* __restrict__ partial, float* __restrict__ f1)
{
    __shared__ float4 Sl[256];
    int t = threadIdx.x;
    int e4 = (blockIdx.x << 2) + (t & 3);
    int ng = t >> 2;
    const float4* p = (const float4*)partial;
    float4 a = {0.f, 0.f, 0.f, 0.f};
#pragma unroll
    for (int i = 0; i < 8; ++i) {
        int ns = ng + (i << 6);
        float4 v = p[(size_t)ns * 1024 + e4];
        a.x += v.x; a.y += v.y; a.z += v.z; a.w += v.w;
    }
    Sl[t] = a;
    __syncthreads();
    for (int off = 128; off >= 4; off >>= 1) {
        if (t < off) {
            float4 u = Sl[t], v = Sl[t + off];
            u.x += v.x; u.y += v.y; u.z += v.z; u.w += v.w;
            Sl[t] = u;
        }
        __syncthreads();
    }
    if (t < 4) ((float4*)f1)[(blockIdx.x << 2) + t] = Sl[t];
}

// ============================ Kernel 4: fc2 =================================
__global__ __launch_bounds__(256) void k_fc2(
    const float* __restrict__ f1, const float* __restrict__ b1,
    const float* __restrict__ w2, const float* __restrict__ b2,
    float* __restrict__ out)
{
    int idx = blockIdx.x * 256 + threadIdx.x;
    if (idx >= 32 * 101) return;
    int b = idx / 101;
    int c = idx - b * 101;
    const float4* fp = (const float4*)(f1 + b * 128);
    const float4* bp = (const float4*)b1;
    const float4* wp = (const float4*)(w2 + c * 128);
    float acc = b2[c];
#pragma unroll
    for (int q = 0; q < 32; ++q) {
        float4 f = fp[q], bb = bp[q], ww = wp[q];
        acc = fmaf(fmaxf(f.x + bb.x, 0.f), ww.x, acc);
        acc = fmaf(fmaxf(f.y + bb.y, 0.f), ww.y, acc);
        acc = fmaf(fmaxf(f.z + bb.z, 0.f), ww.z, acc);
        acc = fmaf(fmaxf(f.w + bb.w, 0.f), ww.w, acc);
    }
    out[idx] = acc;
}

// ================================ launch ====================================
extern "C" void kernel_launch(void* const* d_in, const int* in_sizes, int n_in,
                              void* d_out, int out_size, void* d_ws, size_t ws_size,
                              hipStream_t stream)
{
    const float* x  = (const float*)d_in[0];
    const float* cw = (const float*)d_in[1];
    const float* cb = (const float*)d_in[2];
    const float* gw = (const float*)d_in[3];
    const float* gb = (const float*)d_in[4];
    const float* w1 = (const float*)d_in[5];
    const float* b1 = (const float*)d_in[6];
    const float* w2 = (const float*)d_in[7];
    const float* b2 = (const float*)d_in[8];
    float* out = (float*)d_out;

    float* y       = (float*)d_ws;           // 4,194,304
    float* g       = y + 4194304;            // 8,388,608
    float* partial = g + 8388608;            // 2,097,152 (512 slabs)
    float* f1      = partial + 4194304;      // 4,096

    k_conv_pool<<<512, 256, 0, stream>>>(x, cw, cb, y);
    k_gcn<<<1024, 256, 0, stream>>>(y, gw, gb, g);
    k_fc1<<<512, 256, 0, stream>>>(g, w1, partial);
    k_red<<<256, 256, 0, stream>>>(partial, f1);
    k_fc2<<<13, 256, 0, stream>>>(f1, b1, w2, b2, out);
}